// Round 7
// baseline (5399.677 us; speedup 1.0000x reference)
//
#include <hip/hip_runtime.h>
#include <hip/hip_bf16.h>

#define BATCHN 64
#define SEQ    2048
#define HID    64
#define NF     32
#define DIN    96      // NF + HID
#define G7     448     // 7 * HID
#define CH     33      // time + 32 marks
#define REC_T  256     // 4 waves

using bf16 = __hip_bfloat16;
typedef __attribute__((ext_vector_type(4))) unsigned int u32x4;

__device__ __forceinline__ float b2f(bf16 v) { return __bfloat162float(v); }

// Inputs are float32 (verified R4/R5). flag==1 -> fp32, flag==0 -> bf16.
__device__ __forceinline__ float ldin(const void* p, size_t i, bool f32) {
    return f32 ? ((const float*)p)[i] : b2f(((const bf16*)p)[i]);
}

// Fast math: v_exp/v_rcp based, saturation-safe, NaN-free (verified R5).
__device__ __forceinline__ float fast_rcp(float x) { return __builtin_amdgcn_rcpf(x); }
__device__ __forceinline__ float sigmoid_f(float x) {
    return fast_rcp(1.0f + __expf(-x));
}
__device__ __forceinline__ float tanh_f(float x) {
    float e = __expf(2.0f * x);
    return 1.0f - 2.0f * fast_rcp(e + 1.0f);
}
__device__ __forceinline__ float softplus_f(float x) {
    float e = __expf(-fabsf(x));
    return fmaxf(x, 0.0f) + __logf(1.0f + e);
}

// Broadcast lane k of v to all lanes (uniform k -> v_readlane -> SGPR operand).
__device__ __forceinline__ float rl(float v, int lane) {
    return __uint_as_float(__builtin_amdgcn_readlane(__float_as_uint(v), lane));
}

// Round fp32 to bf16 (RNE), result in HIGH 16 bits (low 16 zero).
__device__ __forceinline__ unsigned int rne_hi16(float f) {
    unsigned int u = __float_as_uint(f);
    return (u + 0x7fffu + ((u >> 16) & 1u)) & 0xffff0000u;
}

#define HI16F(u) __uint_as_float((u) & 0xffff0000u)
#define LO16F(u) __uint_as_float((u) << 16)

__global__ void detect_dtype(const void* batch, int* flag) {
    if (threadIdx.x != 0 || blockIdx.x != 0) return;
    const float* bf = (const float*)batch;
    bool mono = true;
    float prev = bf[0];
    if (!(prev > 0.004f && prev < 1.3f)) mono = false;
    for (int t = 1; t < 16 && mono; ++t) {
        float cur = bf[(size_t)t * CH];
        if (!(cur > prev && (cur - prev) < 1.3f)) mono = false;
        prev = cur;
    }
    *flag = mono ? 1 : 0;
}

// ---------------- weight transpose/pack prep (runs once, ~5 us) -----------
// Wt[c][p] = pack(bf16(W[NF+2p][c]) hi, bf16(W[NF+2p+1][c]) lo), c=0..447,
// p=0..31. Row = 128 B per column -> rec kernel reads a column as 8
// dwordx4. Wt lives in the out_int output region (57 KB), which
// intensity_ws fully overwrites AFTER the rec kernel finishes.
__global__ __launch_bounds__(G7) void wt_prep(
    const void* __restrict__ W_rec, unsigned int* __restrict__ Wt,
    const int* __restrict__ flag)
{
    const bool f32 = *flag != 0;
    const int p = blockIdx.x;      // k-pair 0..31
    const int c = threadIdx.x;     // column 0..447
    unsigned int hi, lo;
    if (f32) {
        const float* W = (const float*)W_rec;
        hi = rne_hi16(W[(size_t)(NF + 2 * p) * G7 + c]);
        lo = rne_hi16(W[(size_t)(NF + 2 * p + 1) * G7 + c]) >> 16;
    } else {
        const unsigned short* W = (const unsigned short*)W_rec;
        hi = ((unsigned int)W[(size_t)(NF + 2 * p) * G7 + c]) << 16;
        lo = (unsigned int)W[(size_t)(NF + 2 * p + 1) * G7 + c];
    }
    Wt[(size_t)c * 32 + p] = hi | lo;
}

// ---------------- x-projection GEMM (fully parallel) ----------------
__global__ __launch_bounds__(G7) void xproj_gemm(
    const void* __restrict__ batch, const void* __restrict__ W_rec,
    const void* __restrict__ b_rec, float* __restrict__ xz,
    const int* __restrict__ flag)
{
    const bool f32 = *flag != 0;
    const int tid = threadIdx.x;
    const size_t base = (size_t)blockIdx.x * 64;   // 64 rows per block

    float wx[NF];
    if (f32) {
        const float* W = (const float*)W_rec;
#pragma unroll
        for (int k = 0; k < NF; ++k) wx[k] = W[(size_t)k * G7 + tid];
    } else {
        const bf16* W = (const bf16*)W_rec;
#pragma unroll
        for (int k = 0; k < NF; ++k) wx[k] = b2f(W[(size_t)k * G7 + tid]);
    }
    const float bias = ldin(b_rec, tid, f32);

    __shared__ __align__(16) float s_x[64][NF];    // 8 KB
    for (int i = tid; i < 64 * NF; i += G7) {
        const int r = i >> 5, k = i & 31;
        s_x[r][k] = ldin(batch, (base + r) * CH + 1 + k, f32);
    }
    __syncthreads();

    for (int r = 0; r < 64; ++r) {
        const float4* xv = (const float4*)s_x[r];
        float a0 = 0.f, a1 = 0.f, a2 = 0.f, a3 = 0.f;
#pragma unroll
        for (int k4 = 0; k4 < NF / 4; ++k4) {
            float4 v = xv[k4];
            a0 = fmaf(v.x, wx[4 * k4 + 0], a0);
            a1 = fmaf(v.y, wx[4 * k4 + 1], a1);
            a2 = fmaf(v.z, wx[4 * k4 + 2], a2);
            a3 = fmaf(v.w, wx[4 * k4 + 3], a3);
        }
        xz[(base + r) * G7 + tid] = bias + ((a0 + a1) + (a2 + a3));
    }
}

// ---------------- recurrent kernel: transposed bf16 weight reloads --------
// R0-R4: 128 scalar dword weight reloads/thread/step from L2, clump-waited
// (~1600 cyc). R5: LDS delivery serialized 512 clk + conflicts + unpack
// (worse). This version: per step, 16 contiguous global_load_dwordx4 of
// bf16-packed transposed weights (64 KB/block/step, half the L2 bytes, 8x
// fewer VMEM instrs), issued in the phase-C region right after the barrier
// so L2 latency hides under phase C; sched_barrier(0) at the loop tail
// keeps the scheduler from sinking them into phase B. CHUNK2 unpack+FMA
// numerics identical to R5 (passed absmax 0.0078125).
__global__ __launch_bounds__(REC_T, 1) void ctlstm_rec_xzt(
    const void* __restrict__ batch, const unsigned int* __restrict__ Wt,
    const float* __restrict__ xz, float* __restrict__ out,
    float* __restrict__ h_ws, const int* __restrict__ flag)
{
    const bool f32 = *flag != 0;
    const int tid  = threadIdx.x;
    const int wave = tid >> 6;      // gate g0 = wave, g1 = wave+4
    const int lane = tid & 63;      // hidden unit j
    const int b    = blockIdx.x;
    const size_t bT = (size_t)b * SEQ;

    float* out_o  = out;
    float* out_c  = out + (size_t)BATCHN * SEQ * HID;
    float* out_cb = out + 2 * (size_t)BATCHN * SEQ * HID;
    float* out_dl = out + 3 * (size_t)BATCHN * SEQ * HID;

    __shared__ float s_act[2][G7];                 // parity double-buffer
    __shared__ float s_times[SEQ];

    const int c0 = tid;                                   // cols 0..255
    const int c1 = (wave < 3) ? tid + 256 : tid;          // cols 256..447

    const u32x4* wp0 = (const u32x4*)Wt + (size_t)c0 * 8; // 8 chunks = 64 k
    const u32x4* wp1 = (const u32x4*)Wt + (size_t)c1 * 8;

    for (int i = tid; i < SEQ; i += REC_T)
        s_times[i] = ldin(batch, (bT + i) * CH, f32);

    float h_reg = 0.0f, c_decay = 0.0f, c_bar = 0.0f;     // per lane j

    // Weight chunks for the CURRENT step (prologue loads t=0's copy).
    u32x4 q0 = wp0[0], q1 = wp0[1], q2 = wp0[2], q3 = wp0[3];
    u32x4 q4 = wp0[4], q5 = wp0[5], q6 = wp0[6], q7 = wp0[7];
    u32x4 r0 = wp1[0], r1 = wp1[1], r2 = wp1[2], r3 = wp1[3];
    u32x4 r4 = wp1[4], r5 = wp1[5], r6 = wp1[6], r7 = wp1[7];

    // xz register pipeline, 2 steps deep (covers HBM/L3 latency).
    float xa0 = xz[bT * G7 + c0];
    float xb0 = xz[bT * G7 + c1];
    float xa1 = xz[(bT + 1) * G7 + c0];
    float xb1 = xz[(bT + 1) * G7 + c1];
    __syncthreads();   // s_times ready (once, outside the hot loop)

// chunk i covers k = 8i..8i+7: dword j of the u32x4 packs (k=8i+2j) in the
// high 16 bits and (k=8i+2j+1) in the low 16 bits.
#define CHUNK2(QX, QY, KB) { \
    float hh; unsigned int ux, uy; \
    ux = (QX)[0]; uy = (QY)[0]; \
    hh = rl(h_reg, (KB)+0); a0x = fmaf(hh, HI16F(ux), a0x); a0y = fmaf(hh, HI16F(uy), a0y); \
    hh = rl(h_reg, (KB)+1); a1x = fmaf(hh, LO16F(ux), a1x); a1y = fmaf(hh, LO16F(uy), a1y); \
    ux = (QX)[1]; uy = (QY)[1]; \
    hh = rl(h_reg, (KB)+2); a0x = fmaf(hh, HI16F(ux), a0x); a0y = fmaf(hh, HI16F(uy), a0y); \
    hh = rl(h_reg, (KB)+3); a1x = fmaf(hh, LO16F(ux), a1x); a1y = fmaf(hh, LO16F(uy), a1y); \
    ux = (QX)[2]; uy = (QY)[2]; \
    hh = rl(h_reg, (KB)+4); a0x = fmaf(hh, HI16F(ux), a0x); a0y = fmaf(hh, HI16F(uy), a0y); \
    hh = rl(h_reg, (KB)+5); a1x = fmaf(hh, LO16F(ux), a1x); a1y = fmaf(hh, LO16F(uy), a1y); \
    ux = (QX)[3]; uy = (QY)[3]; \
    hh = rl(h_reg, (KB)+6); a0x = fmaf(hh, HI16F(ux), a0x); a0y = fmaf(hh, HI16F(uy), a0y); \
    hh = rl(h_reg, (KB)+7); a1x = fmaf(hh, LO16F(ux), a1x); a1y = fmaf(hh, LO16F(uy), a1y); }

    for (int t = 0; t < SEQ; ++t) {
        // ---- Phase B: z = xz + dot(h, W); h broadcast via readlane.
        float a0x = 0.f, a1x = 0.f, a0y = 0.f, a1y = 0.f;
        CHUNK2(q0, r0, 0)  CHUNK2(q1, r1, 8)  CHUNK2(q2, r2, 16) CHUNK2(q3, r3, 24)
        CHUNK2(q4, r4, 32) CHUNK2(q5, r5, 40) CHUNK2(q6, r6, 48) CHUNK2(q7, r7, 56)
        const float z0 = xa0 + (a0x + a1x);
        const float z1 = xb0 + (a0y + a1y);

        // g0 = wave: 0:i 1:f 2:g(tanh) 3:o ; g1 = wave+4: 4:ibar 5:fbar 6:delta
        const float act0 = (wave == 2) ? tanh_f(z0) : sigmoid_f(z0);
        const float act1 = (wave == 2) ? softplus_f(z1) : sigmoid_f(z1);

        const int p = t & 1;
        s_act[p][c0] = act0;
        if (wave < 3) s_act[p][c1] = act1;

        // R1-style barrier (fastest measured): drain own LDS write, barrier.
        asm volatile("s_waitcnt lgkmcnt(0)" ::: "memory");
        __builtin_amdgcn_s_barrier();
        __builtin_amdgcn_sched_barrier(0);

        // ---- Weight reload for NEXT step: 16 dwordx4, issued here so L2
        // latency hides under phase C. Addresses are loop-invariant.
        q0 = wp0[0]; q1 = wp0[1]; q2 = wp0[2]; q3 = wp0[3];
        q4 = wp0[4]; q5 = wp0[5]; q6 = wp0[6]; q7 = wp0[7];
        r0 = wp1[0]; r1 = wp1[1]; r2 = wp1[2]; r3 = wp1[3];
        r4 = wp1[4]; r5 = wp1[5]; r6 = wp1[6]; r7 = wp1[7];

        // xz prefetch for t+2 (register pipeline).
        float xa2 = 0.0f, xb2 = 0.0f;
        if (t + 2 < SEQ) {
            xa2 = xz[(bT + t + 2) * G7 + c0];
            xb2 = xz[(bT + t + 2) * G7 + c1];
        }

        // ---- Phase C: replicated in every wave for hidden unit j = lane.
        const float ig = s_act[p][lane];
        const float fg = s_act[p][HID + lane];
        const float gg = s_act[p][2 * HID + lane];
        const float og = s_act[p][3 * HID + lane];
        const float ib = s_act[p][4 * HID + lane];
        const float fb = s_act[p][5 * HID + lane];
        const float dl = s_act[p][6 * HID + lane];
        const float c   = fg * c_decay + ig * gg;
        const float cbn = fb * c_bar + ib * gg;
        float dt = (t + 1 < SEQ) ? (s_times[t + 1] - s_times[t]) : 0.0f;
        dt = fmaxf(dt, 0.0f);
        const float cd = cbn + (c - cbn) * __expf(-dl * dt);
        const float h  = og * tanh_f(cd);
        c_decay = cd;
        c_bar   = cbn;
        h_reg   = h;

        // Fire-and-forget stores (no barrier drain on the critical path).
        const size_t idx = (bT + t) * HID + lane;
        if (wave == 0)      out_c[idx]  = c;
        else if (wave == 1) out_cb[idx] = cbn;
        else if (wave == 2) h_ws[idx]   = h;
        else                { out_o[idx] = og; out_dl[idx] = dl; }

        xa0 = xa1; xb0 = xb1; xa1 = xa2; xb1 = xb2;

        // Keep the weight reloads anchored in the phase-C region: nothing
        // may be scheduled across this point (blocks sink-to-use).
        __builtin_amdgcn_sched_barrier(0);
    }
#undef CHUNK2
}

// ---------------- fallback recurrent kernel (R5 structure, no xz ws) --------
__global__ __launch_bounds__(G7, 2) void ctlstm_rec(
    const void* __restrict__ batch, const void* __restrict__ W_rec,
    const void* __restrict__ b_rec, float* __restrict__ out,
    float* __restrict__ h_ws, int use_ws, const int* __restrict__ flag)
{
    const bool f32 = flag ? (*flag != 0) : true;
    const int tid = threadIdx.x;
    const int b   = blockIdx.x;
    const size_t bT = (size_t)b * SEQ;

    float* out_o  = out;
    float* out_c  = out + (size_t)BATCHN * SEQ * HID;
    float* out_cb = out + 2 * (size_t)BATCHN * SEQ * HID;
    float* out_dl = out + 3 * (size_t)BATCHN * SEQ * HID;

    __shared__ __align__(16) float s_in[DIN];
    __shared__ float s_act[G7];
    __shared__ float s_times[SEQ];

    float wcol[DIN];
    if (f32) {
        const float* W = (const float*)W_rec;
#pragma unroll
        for (int k = 0; k < DIN; ++k) wcol[k] = W[(size_t)k * G7 + tid];
    } else {
        const bf16* W = (const bf16*)W_rec;
#pragma unroll
        for (int k = 0; k < DIN; ++k) wcol[k] = b2f(W[(size_t)k * G7 + tid]);
    }
    const float bias = ldin(b_rec, tid, f32);

    for (int i = tid; i < SEQ; i += G7)
        s_times[i] = ldin(batch, (bT + i) * CH, f32);

    if (tid >= NF && tid < DIN) s_in[tid] = 0.0f;
    float c_decay = 0.0f, c_bar = 0.0f;

    float xpref = 0.0f;
    if (tid < NF) xpref = ldin(batch, bT * CH + 1 + tid, f32);
    __syncthreads();

    const int gate = tid >> 6;
    const int lane = tid & 63;

    for (int t = 0; t < SEQ; ++t) {
        if (tid < NF) s_in[tid] = xpref;
        __syncthreads();

        const float4* sv = (const float4*)s_in;
        float a0 = 0.f, a1 = 0.f, a2 = 0.f, a3 = 0.f;
#pragma unroll
        for (int k4 = 0; k4 < DIN / 4; ++k4) {
            float4 v = sv[k4];
            a0 = fmaf(v.x, wcol[4 * k4 + 0], a0);
            a1 = fmaf(v.y, wcol[4 * k4 + 1], a1);
            a2 = fmaf(v.z, wcol[4 * k4 + 2], a2);
            a3 = fmaf(v.w, wcol[4 * k4 + 3], a3);
        }
        const float z = bias + ((a0 + a1) + (a2 + a3));

        float act;
        if (gate == 2)      act = tanh_f(z);
        else if (gate == 6) act = softplus_f(z);
        else                act = sigmoid_f(z);
        s_act[tid] = act;

        const size_t oidx = (bT + t) * HID + lane;
        if (gate == 3) out_o[oidx]  = act;
        if (gate == 6) out_dl[oidx] = act;
        __syncthreads();

        if (tid < HID) {
            const float ig = s_act[tid];
            const float fg = s_act[HID + tid];
            const float gg = s_act[2 * HID + tid];
            const float og = s_act[3 * HID + tid];
            const float ib = s_act[4 * HID + tid];
            const float fb = s_act[5 * HID + tid];
            const float dl = s_act[6 * HID + tid];
            const float c  = fg * c_decay + ig * gg;
            const float cb = fb * c_bar + ib * gg;
            float dt = (t + 1 < SEQ) ? (s_times[t + 1] - s_times[t]) : 0.0f;
            dt = fmaxf(dt, 0.0f);
            const float cd = cb + (c - cb) * __expf(-dl * dt);
            const float h  = og * tanh_f(cd);
            c_decay = cd;
            c_bar   = cb;
            s_in[NF + tid] = h;
            const size_t idx = (bT + t) * HID + tid;
            out_c[idx]  = c;
            out_cb[idx] = cb;
            if (use_ws) h_ws[idx] = h;
        }
        if (tid < NF && t + 1 < SEQ)
            xpref = ldin(batch, (bT + t + 1) * CH + 1 + tid, f32);
    }
}

// ---------------- intensity head ----------------
__global__ __launch_bounds__(256) void intensity_ws(
    const float* __restrict__ h_ws, const void* __restrict__ W_int,
    const void* __restrict__ b_int, float* __restrict__ out_int,
    const int* __restrict__ flag)
{
    const bool f32 = flag ? (*flag != 0) : true;
    __shared__ float s_w[HID * NF];
    __shared__ float s_b[NF];
    const int tx = threadIdx.x, ty = threadIdx.y;
    const int lt = ty * 32 + tx;
    for (int k = lt; k < HID * NF; k += 256) s_w[k] = ldin(W_int, k, f32);
    if (lt < NF) s_b[lt] = ldin(b_int, lt, f32);
    __syncthreads();

    const int b = blockIdx.y;
    const int t = blockIdx.x * 8 + ty;
    if (t >= SEQ - 1) return;
    const float* hr = h_ws + ((size_t)b * SEQ + t) * HID;
    float acc = s_b[tx];
#pragma unroll
    for (int k = 0; k < HID; ++k) acc = fmaf(hr[k], s_w[k * NF + tx], acc);
    out_int[((size_t)b * (SEQ - 1) + t) * NF + tx] = softplus_f(acc);
}

__global__ __launch_bounds__(256) void intensity_rec(
    const void* __restrict__ batch, const float* __restrict__ out,
    const void* __restrict__ W_int, const void* __restrict__ b_int,
    float* __restrict__ out_int, const int* __restrict__ flag)
{
    const bool f32 = flag ? (*flag != 0) : true;
    __shared__ float s_w[HID * NF];
    __shared__ float s_b[NF];
    __shared__ float s_h[8][HID];
    const int tx = threadIdx.x, ty = threadIdx.y;
    const int lt = ty * 32 + tx;
    for (int k = lt; k < HID * NF; k += 256) s_w[k] = ldin(W_int, k, f32);
    if (lt < NF) s_b[lt] = ldin(b_int, lt, f32);

    const int b  = blockIdx.y;
    const int t0 = blockIdx.x * 8;
    const float* out_o  = out;
    const float* out_c  = out + (size_t)BATCHN * SEQ * HID;
    const float* out_cb = out + 2 * (size_t)BATCHN * SEQ * HID;
    const float* out_dl = out + 3 * (size_t)BATCHN * SEQ * HID;

#pragma unroll
    for (int r = 0; r < 2; ++r) {
        const int flat = lt + r * 256;
        const int row  = flat >> 6;
        const int k    = flat & 63;
        const int t    = t0 + row;
        if (t < SEQ - 1) {
            const size_t idx = ((size_t)b * SEQ + t) * HID + k;
            const float og = out_o[idx];
            const float c  = out_c[idx];
            const float cb = out_cb[idx];
            const float dl = out_dl[idx];
            const float t_a = ldin(batch, ((size_t)b * SEQ + t) * CH, f32);
            const float t_b = ldin(batch, ((size_t)b * SEQ + t + 1) * CH, f32);
            const float dt = fmaxf(t_b - t_a, 0.0f);
            const float cd = cb + (c - cb) * __expf(-dl * dt);
            s_h[row][k] = og * tanh_f(cd);
        }
    }
    __syncthreads();
    const int t = t0 + ty;
    if (t >= SEQ - 1) return;
    float acc = s_b[tx];
#pragma unroll
    for (int k = 0; k < HID; ++k) acc = fmaf(s_h[ty][k], s_w[k * NF + tx], acc);
    out_int[((size_t)b * (SEQ - 1) + t) * NF + tx] = softplus_f(acc);
}

extern "C" void kernel_launch(void* const* d_in, const int* in_sizes, int n_in,
                              void* d_out, int out_size, void* d_ws, size_t ws_size,
                              hipStream_t stream) {
    const void* batch = d_in[0];
    const void* W_rec = d_in[1];
    const void* b_rec = d_in[2];
    const void* W_int = d_in[3];
    const void* b_int = d_in[4];
    float* out = (float*)d_out;

    // ws layout: [0,256) flag | [256, 256+hb) fp32 h | [256+hb, ...) xz fp32
    const size_t hb  = (size_t)BATCHN * SEQ * HID * sizeof(float);   // 33.5 MB
    const size_t xzb = (size_t)BATCHN * SEQ * G7  * sizeof(float);   // 235 MB
    int*   flag = (ws_size >= 4) ? (int*)d_ws : nullptr;
    float* h_ws = (float*)((char*)d_ws + 256);
    float* xz   = (float*)((char*)d_ws + 256 + hb);
    const int have_h  = (ws_size >= 256 + hb) ? 1 : 0;          // launch-constant
    const int have_xz = (ws_size >= 256 + hb + xzb) ? 1 : 0;    // launch-constant

    if (flag) detect_dtype<<<1, 64, 0, stream>>>(batch, flag);

    float* out_int = out + 4 * (size_t)BATCHN * SEQ * HID;
    // Packed transposed weights (57 KB) live at the start of out_int; the
    // rec kernel reads them, then intensity_ws fully overwrites the region.
    unsigned int* Wt = (unsigned int*)out_int;

    if (have_xz) {
        wt_prep<<<32, G7, 0, stream>>>(W_rec, Wt, flag);
        xproj_gemm<<<(BATCHN * SEQ) / 64, G7, 0, stream>>>(batch, W_rec, b_rec, xz, flag);
        ctlstm_rec_xzt<<<BATCHN, REC_T, 0, stream>>>(batch, Wt, xz, out, h_ws, flag);
        intensity_ws<<<dim3((SEQ - 1 + 7) / 8, BATCHN), dim3(32, 8), 0, stream>>>(
            h_ws, W_int, b_int, out_int, flag);
    } else if (have_h) {
        ctlstm_rec<<<BATCHN, G7, 0, stream>>>(batch, W_rec, b_rec, out, h_ws, 1, flag);
        intensity_ws<<<dim3((SEQ - 1 + 7) / 8, BATCHN), dim3(32, 8), 0, stream>>>(
            h_ws, W_int, b_int, out_int, flag);
    } else {
        ctlstm_rec<<<BATCHN, G7, 0, stream>>>(batch, W_rec, b_rec, out, h_ws, 0, flag);
        intensity_rec<<<dim3((SEQ - 1 + 7) / 8, BATCHN), dim3(32, 8), 0, stream>>>(
            batch, out, W_int, b_int, out_int, flag);
    }
}

// Round 8
// 3143.993 us; speedup vs baseline: 1.7175x; 1.7175x over previous
//
#include <hip/hip_runtime.h>
#include <hip/hip_bf16.h>

#define BATCHN 64
#define SEQ    2048
#define HID    64
#define NF     32
#define DIN    96      // NF + HID
#define G7     448     // 7 * HID
#define CH     33      // time + 32 marks
#define REC_T  256     // 4 waves

using bf16 = __hip_bfloat16;
typedef __attribute__((ext_vector_type(4))) unsigned int u32x4;

__device__ __forceinline__ float b2f(bf16 v) { return __bfloat162float(v); }

// Inputs are float32 (verified R4/R5). flag==1 -> fp32, flag==0 -> bf16.
__device__ __forceinline__ float ldin(const void* p, size_t i, bool f32) {
    return f32 ? ((const float*)p)[i] : b2f(((const bf16*)p)[i]);
}

// Fast math: v_exp/v_rcp based, saturation-safe, NaN-free (verified R5).
__device__ __forceinline__ float fast_rcp(float x) { return __builtin_amdgcn_rcpf(x); }
__device__ __forceinline__ float sigmoid_f(float x) {
    return fast_rcp(1.0f + __expf(-x));
}
__device__ __forceinline__ float tanh_f(float x) {
    float e = __expf(2.0f * x);
    return 1.0f - 2.0f * fast_rcp(e + 1.0f);
}
__device__ __forceinline__ float softplus_f(float x) {
    float e = __expf(-fabsf(x));
    return fmaxf(x, 0.0f) + __logf(1.0f + e);
}

// Round fp32 to bf16 (RNE), result in HIGH 16 bits (low 16 zero).
__device__ __forceinline__ unsigned int rne_hi16(float f) {
    unsigned int u = __float_as_uint(f);
    return (u + 0x7fffu + ((u >> 16) & 1u)) & 0xffff0000u;
}

#define HI16F(u) __uint_as_float((u) & 0xffff0000u)
#define LO16F(u) __uint_as_float((u) << 16)

__global__ void detect_dtype(const void* batch, int* flag) {
    if (threadIdx.x != 0 || blockIdx.x != 0) return;
    const float* bf = (const float*)batch;
    bool mono = true;
    float prev = bf[0];
    if (!(prev > 0.004f && prev < 1.3f)) mono = false;
    for (int t = 1; t < 16 && mono; ++t) {
        float cur = bf[(size_t)t * CH];
        if (!(cur > prev && (cur - prev) < 1.3f)) mono = false;
        prev = cur;
    }
    *flag = mono ? 1 : 0;
}

// ---------------- x-projection GEMM (fully parallel) ----------------
__global__ __launch_bounds__(G7) void xproj_gemm(
    const void* __restrict__ batch, const void* __restrict__ W_rec,
    const void* __restrict__ b_rec, float* __restrict__ xz,
    const int* __restrict__ flag)
{
    const bool f32 = *flag != 0;
    const int tid = threadIdx.x;
    const size_t base = (size_t)blockIdx.x * 64;   // 64 rows per block

    float wx[NF];
    if (f32) {
        const float* W = (const float*)W_rec;
#pragma unroll
        for (int k = 0; k < NF; ++k) wx[k] = W[(size_t)k * G7 + tid];
    } else {
        const bf16* W = (const bf16*)W_rec;
#pragma unroll
        for (int k = 0; k < NF; ++k) wx[k] = b2f(W[(size_t)k * G7 + tid]);
    }
    const float bias = ldin(b_rec, tid, f32);

    __shared__ __align__(16) float s_x[64][NF];    // 8 KB
    for (int i = tid; i < 64 * NF; i += G7) {
        const int r = i >> 5, k = i & 31;
        s_x[r][k] = ldin(batch, (base + r) * CH + 1 + k, f32);
    }
    __syncthreads();

    for (int r = 0; r < 64; ++r) {
        const float4* xv = (const float4*)s_x[r];
        float a0 = 0.f, a1 = 0.f, a2 = 0.f, a3 = 0.f;
#pragma unroll
        for (int k4 = 0; k4 < NF / 4; ++k4) {
            float4 v = xv[k4];
            a0 = fmaf(v.x, wx[4 * k4 + 0], a0);
            a1 = fmaf(v.y, wx[4 * k4 + 1], a1);
            a2 = fmaf(v.z, wx[4 * k4 + 2], a2);
            a3 = fmaf(v.w, wx[4 * k4 + 3], a3);
        }
        xz[(base + r) * G7 + tid] = bias + ((a0 + a1) + (a2 + a3));
    }
}

// ---------------- recurrent kernel: LDS weights, conflict-free layout -----
// R0-R4: compiler refuses register residency (VGPR 80, L2 reloads ~131KB/
// step/CU at ~56B/clk = the 1772cyc wall). R7: prefetch regs spilled to
// scratch (worse). R5: LDS idea right, layout wrong (per-thread-256B blocks
// -> 8 bank groups -> 8.4M conflict cyc) + readlane/unpack overhead.
// THIS version: chunk-major/lane-minor LDS layout so each wave-wide
// ds_read_b128 covers 1024 CONSECUTIVE bytes (2 lanes/bank = conflict-free,
// 64KB/step at 128-256B/clk, overlapped with FMA). h is broadcast from a
// wave-private LDS copy (uniform-addr read = broadcast, no readlane). No
// large values live across the barrier -> nothing for the RA to spill.
__global__ __launch_bounds__(REC_T, 1) void ctlstm_rec_xzw(
    const void* __restrict__ batch, const void* __restrict__ W_rec,
    const float* __restrict__ xz, float* __restrict__ out,
    float* __restrict__ h_ws, const int* __restrict__ flag)
{
    const bool f32 = *flag != 0;
    const int tid  = threadIdx.x;
    const int wave = tid >> 6;      // gate g0 = wave, g1 = wave+4
    const int lane = tid & 63;      // hidden unit j, and own column index
    const int b    = blockIdx.x;
    const size_t bT = (size_t)b * SEQ;

    float* out_o  = out;
    float* out_c  = out + (size_t)BATCHN * SEQ * HID;
    float* out_cb = out + 2 * (size_t)BATCHN * SEQ * HID;
    float* out_dl = out + 3 * (size_t)BATCHN * SEQ * HID;

    // X region: dword (wave*8+j)*256 + lane*4 + p  (32 KB, all 4 waves)
    // Y region: 8192 + same (24 KB, waves 0-2; wave 3's y == x)
    __shared__ __align__(16) unsigned int s_w[14336];   // 56 KB
    __shared__ __align__(16) float s_h[4 * HID];        // 1 KB wave-private h
    __shared__ float s_act[2][G7];                      // 3.5 KB parity buffer

    const int c0 = wave * 64 + lane;                      // cols 0..255
    const int c1 = (wave < 3) ? c0 + 256 : c0;            // cols 256..447

    // ---- pack h-part weights into LDS (bf16 RNE, 2 per dword) ----
    if (f32) {
        const float* W = (const float*)W_rec;
        for (int j = 0; j < 8; ++j)
            for (int p = 0; p < 4; ++p) {
                const int ke = 8 * j + 2 * p;
                unsigned int hi = rne_hi16(W[(size_t)(NF + ke) * G7 + c0]);
                unsigned int lo = rne_hi16(W[(size_t)(NF + ke + 1) * G7 + c0]) >> 16;
                s_w[(wave * 8 + j) * 256 + lane * 4 + p] = hi | lo;
                if (wave < 3) {
                    unsigned int hy = rne_hi16(W[(size_t)(NF + ke) * G7 + c1]);
                    unsigned int ly = rne_hi16(W[(size_t)(NF + ke + 1) * G7 + c1]) >> 16;
                    s_w[8192 + (wave * 8 + j) * 256 + lane * 4 + p] = hy | ly;
                }
            }
    } else {
        const unsigned short* W = (const unsigned short*)W_rec;
        for (int j = 0; j < 8; ++j)
            for (int p = 0; p < 4; ++p) {
                const int ke = 8 * j + 2 * p;
                unsigned int hi = ((unsigned int)W[(size_t)(NF + ke) * G7 + c0]) << 16;
                unsigned int lo = (unsigned int)W[(size_t)(NF + ke + 1) * G7 + c0];
                s_w[(wave * 8 + j) * 256 + lane * 4 + p] = hi | lo;
                if (wave < 3) {
                    unsigned int hy = ((unsigned int)W[(size_t)(NF + ke) * G7 + c1]) << 16;
                    unsigned int ly = (unsigned int)W[(size_t)(NF + ke + 1) * G7 + c1];
                    s_w[8192 + (wave * 8 + j) * 256 + lane * 4 + p] = hy | ly;
                }
            }
    }
    s_h[wave * HID + lane] = 0.0f;                       // h0 (own wave's copy)

    float c_decay = 0.0f, c_bar = 0.0f;                  // per lane j

    // Byte bases for the per-step LDS reads (loop-invariant).
    const unsigned int xb = (unsigned int)(wave * 8192 + lane * 16);
    const unsigned int yb = (wave < 3) ? (unsigned int)(32768 + wave * 8192 + lane * 16) : xb;
    const char* swb = (const char*)s_w;
    const char* shb = (const char*)s_h + wave * 256;     // own wave's h copy

    // xz register pipeline, 2 steps deep (covers HBM/L3 latency).
    float xa0 = xz[bT * G7 + c0];
    float xb0 = xz[bT * G7 + c1];
    float xa1 = xz[(bT + 1) * G7 + c0];
    float xb1 = xz[(bT + 1) * G7 + c1];
    // times: uniform-address loads, register rotation (R5-proven).
    float tmc = ldin(batch, (bT + 0) * CH, f32);
    float tmn = ldin(batch, (bT + 1) * CH, f32);
    __syncthreads();   // s_w + s_h ready

// chunk j covers k = 8j..8j+7; dword p packs (k=8j+2p) hi / (k=8j+2p+1) lo.
#define WCHUNK(j) { \
    const float4 ha = *(const float4*)(shb + (j) * 32);        /* h[8j..8j+3] */ \
    const float4 hb = *(const float4*)(shb + (j) * 32 + 16);   /* h[8j+4..8j+7] */ \
    const u32x4 qx = *(const u32x4*)(swb + xb + (j) * 1024); \
    const u32x4 qy = *(const u32x4*)(swb + yb + (j) * 1024); \
    a0x = fmaf(ha.x, HI16F(qx[0]), a0x); a1x = fmaf(ha.y, LO16F(qx[0]), a1x); \
    a0y = fmaf(ha.x, HI16F(qy[0]), a0y); a1y = fmaf(ha.y, LO16F(qy[0]), a1y); \
    a0x = fmaf(ha.z, HI16F(qx[1]), a0x); a1x = fmaf(ha.w, LO16F(qx[1]), a1x); \
    a0y = fmaf(ha.z, HI16F(qy[1]), a0y); a1y = fmaf(ha.w, LO16F(qy[1]), a1y); \
    a0x = fmaf(hb.x, HI16F(qx[2]), a0x); a1x = fmaf(hb.y, LO16F(qx[2]), a1x); \
    a0y = fmaf(hb.x, HI16F(qy[2]), a0y); a1y = fmaf(hb.y, LO16F(qy[2]), a1y); \
    a0x = fmaf(hb.z, HI16F(qx[3]), a0x); a1x = fmaf(hb.w, LO16F(qx[3]), a1x); \
    a0y = fmaf(hb.z, HI16F(qy[3]), a0y); a1y = fmaf(hb.w, LO16F(qy[3]), a1y); }

    for (int t = 0; t < SEQ; ++t) {
        // Prefetch xz for t+2 and time for t+2 (register pipelines).
        float xa2 = 0.0f, xb2 = 0.0f;
        if (t + 2 < SEQ) {
            xa2 = xz[(bT + t + 2) * G7 + c0];
            xb2 = xz[(bT + t + 2) * G7 + c1];
        }
        const int tp2 = (t + 2 < SEQ) ? (t + 2) : (SEQ - 1);
        const float tm2 = ldin(batch, (bT + tp2) * CH, f32);

        // ---- Phase B: z = xz + dot(h, W); weights + h streamed from LDS.
        float a0x = 0.f, a1x = 0.f, a0y = 0.f, a1y = 0.f;
        WCHUNK(0) WCHUNK(1) WCHUNK(2) WCHUNK(3)
        WCHUNK(4) WCHUNK(5) WCHUNK(6) WCHUNK(7)
        const float z0 = xa0 + (a0x + a1x);
        const float z1 = xb0 + (a0y + a1y);

        // g0 = wave: 0:i 1:f 2:g(tanh) 3:o ; g1 = wave+4: 4:ibar 5:fbar 6:delta
        const float act0 = (wave == 2) ? tanh_f(z0) : sigmoid_f(z0);
        const float act1 = (wave == 2) ? softplus_f(z1) : sigmoid_f(z1);

        const int p = t & 1;
        s_act[p][c0] = act0;
        if (wave < 3) s_act[p][c1] = act1;

        // Raw barrier (R2-proven form): drain own LDS writes, barrier, pin.
        __builtin_amdgcn_sched_barrier(0);
        asm volatile("s_waitcnt lgkmcnt(0)");
        __builtin_amdgcn_s_barrier();
        __builtin_amdgcn_sched_barrier(0);

        // ---- Phase C: replicated in every wave for hidden unit j = lane.
        const float ig = s_act[p][lane];
        const float fg = s_act[p][HID + lane];
        const float gg = s_act[p][2 * HID + lane];
        const float og = s_act[p][3 * HID + lane];
        const float ib = s_act[p][4 * HID + lane];
        const float fb = s_act[p][5 * HID + lane];
        const float dl = s_act[p][6 * HID + lane];
        const float c   = fg * c_decay + ig * gg;
        const float cbn = fb * c_bar + ib * gg;
        const float dt  = fmaxf(tmn - tmc, 0.0f);
        const float cd = cbn + (c - cbn) * __expf(-dl * dt);
        const float h  = og * tanh_f(cd);
        c_decay = cd;
        c_bar   = cbn;
        s_h[wave * HID + lane] = h;    // own wave's copy; read next step (same wave)

        // Fire-and-forget stores (no barrier drain on the critical path).
        const size_t idx = (bT + t) * HID + lane;
        if (wave == 0)      out_c[idx]  = c;
        else if (wave == 1) out_cb[idx] = cbn;
        else if (wave == 2) h_ws[idx]   = h;
        else                { out_o[idx] = og; out_dl[idx] = dl; }

        xa0 = xa1; xb0 = xb1; xa1 = xa2; xb1 = xb2;
        tmc = tmn; tmn = tm2;
    }
#undef WCHUNK
}

// ---------------- fallback recurrent kernel (R5 structure, no xz ws) --------
__global__ __launch_bounds__(G7, 2) void ctlstm_rec(
    const void* __restrict__ batch, const void* __restrict__ W_rec,
    const void* __restrict__ b_rec, float* __restrict__ out,
    float* __restrict__ h_ws, int use_ws, const int* __restrict__ flag)
{
    const bool f32 = flag ? (*flag != 0) : true;
    const int tid = threadIdx.x;
    const int b   = blockIdx.x;
    const size_t bT = (size_t)b * SEQ;

    float* out_o  = out;
    float* out_c  = out + (size_t)BATCHN * SEQ * HID;
    float* out_cb = out + 2 * (size_t)BATCHN * SEQ * HID;
    float* out_dl = out + 3 * (size_t)BATCHN * SEQ * HID;

    __shared__ __align__(16) float s_in[DIN];
    __shared__ float s_act[G7];
    __shared__ float s_times[SEQ];

    float wcol[DIN];
    if (f32) {
        const float* W = (const float*)W_rec;
#pragma unroll
        for (int k = 0; k < DIN; ++k) wcol[k] = W[(size_t)k * G7 + tid];
    } else {
        const bf16* W = (const bf16*)W_rec;
#pragma unroll
        for (int k = 0; k < DIN; ++k) wcol[k] = b2f(W[(size_t)k * G7 + tid]);
    }
    const float bias = ldin(b_rec, tid, f32);

    for (int i = tid; i < SEQ; i += G7)
        s_times[i] = ldin(batch, (bT + i) * CH, f32);

    if (tid >= NF && tid < DIN) s_in[tid] = 0.0f;
    float c_decay = 0.0f, c_bar = 0.0f;

    float xpref = 0.0f;
    if (tid < NF) xpref = ldin(batch, bT * CH + 1 + tid, f32);
    __syncthreads();

    const int gate = tid >> 6;
    const int lane = tid & 63;

    for (int t = 0; t < SEQ; ++t) {
        if (tid < NF) s_in[tid] = xpref;
        __syncthreads();

        const float4* sv = (const float4*)s_in;
        float a0 = 0.f, a1 = 0.f, a2 = 0.f, a3 = 0.f;
#pragma unroll
        for (int k4 = 0; k4 < DIN / 4; ++k4) {
            float4 v = sv[k4];
            a0 = fmaf(v.x, wcol[4 * k4 + 0], a0);
            a1 = fmaf(v.y, wcol[4 * k4 + 1], a1);
            a2 = fmaf(v.z, wcol[4 * k4 + 2], a2);
            a3 = fmaf(v.w, wcol[4 * k4 + 3], a3);
        }
        const float z = bias + ((a0 + a1) + (a2 + a3));

        float act;
        if (gate == 2)      act = tanh_f(z);
        else if (gate == 6) act = softplus_f(z);
        else                act = sigmoid_f(z);
        s_act[tid] = act;

        const size_t oidx = (bT + t) * HID + lane;
        if (gate == 3) out_o[oidx]  = act;
        if (gate == 6) out_dl[oidx] = act;
        __syncthreads();

        if (tid < HID) {
            const float ig = s_act[tid];
            const float fg = s_act[HID + tid];
            const float gg = s_act[2 * HID + tid];
            const float og = s_act[3 * HID + tid];
            const float ib = s_act[4 * HID + tid];
            const float fb = s_act[5 * HID + tid];
            const float dl = s_act[6 * HID + tid];
            const float c  = fg * c_decay + ig * gg;
            const float cb = fb * c_bar + ib * gg;
            float dt = (t + 1 < SEQ) ? (s_times[t + 1] - s_times[t]) : 0.0f;
            dt = fmaxf(dt, 0.0f);
            const float cd = cb + (c - cb) * __expf(-dl * dt);
            const float h  = og * tanh_f(cd);
            c_decay = cd;
            c_bar   = cb;
            s_in[NF + tid] = h;
            const size_t idx = (bT + t) * HID + tid;
            out_c[idx]  = c;
            out_cb[idx] = cb;
            if (use_ws) h_ws[idx] = h;
        }
        if (tid < NF && t + 1 < SEQ)
            xpref = ldin(batch, (bT + t + 1) * CH + 1 + tid, f32);
    }
}

// ---------------- intensity head ----------------
__global__ __launch_bounds__(256) void intensity_ws(
    const float* __restrict__ h_ws, const void* __restrict__ W_int,
    const void* __restrict__ b_int, float* __restrict__ out_int,
    const int* __restrict__ flag)
{
    const bool f32 = flag ? (*flag != 0) : true;
    __shared__ float s_w[HID * NF];
    __shared__ float s_b[NF];
    const int tx = threadIdx.x, ty = threadIdx.y;
    const int lt = ty * 32 + tx;
    for (int k = lt; k < HID * NF; k += 256) s_w[k] = ldin(W_int, k, f32);
    if (lt < NF) s_b[lt] = ldin(b_int, lt, f32);
    __syncthreads();

    const int b = blockIdx.y;
    const int t = blockIdx.x * 8 + ty;
    if (t >= SEQ - 1) return;
    const float* hr = h_ws + ((size_t)b * SEQ + t) * HID;
    float acc = s_b[tx];
#pragma unroll
    for (int k = 0; k < HID; ++k) acc = fmaf(hr[k], s_w[k * NF + tx], acc);
    out_int[((size_t)b * (SEQ - 1) + t) * NF + tx] = softplus_f(acc);
}

__global__ __launch_bounds__(256) void intensity_rec(
    const void* __restrict__ batch, const float* __restrict__ out,
    const void* __restrict__ W_int, const void* __restrict__ b_int,
    float* __restrict__ out_int, const int* __restrict__ flag)
{
    const bool f32 = flag ? (*flag != 0) : true;
    __shared__ float s_w[HID * NF];
    __shared__ float s_b[NF];
    __shared__ float s_h[8][HID];
    const int tx = threadIdx.x, ty = threadIdx.y;
    const int lt = ty * 32 + tx;
    for (int k = lt; k < HID * NF; k += 256) s_w[k] = ldin(W_int, k, f32);
    if (lt < NF) s_b[lt] = ldin(b_int, lt, f32);

    const int b  = blockIdx.y;
    const int t0 = blockIdx.x * 8;
    const float* out_o  = out;
    const float* out_c  = out + (size_t)BATCHN * SEQ * HID;
    const float* out_cb = out + 2 * (size_t)BATCHN * SEQ * HID;
    const float* out_dl = out + 3 * (size_t)BATCHN * SEQ * HID;

#pragma unroll
    for (int r = 0; r < 2; ++r) {
        const int flat = lt + r * 256;
        const int row  = flat >> 6;
        const int k    = flat & 63;
        const int t    = t0 + row;
        if (t < SEQ - 1) {
            const size_t idx = ((size_t)b * SEQ + t) * HID + k;
            const float og = out_o[idx];
            const float c  = out_c[idx];
            const float cb = out_cb[idx];
            const float dl = out_dl[idx];
            const float t_a = ldin(batch, ((size_t)b * SEQ + t) * CH, f32);
            const float t_b = ldin(batch, ((size_t)b * SEQ + t + 1) * CH, f32);
            const float dt = fmaxf(t_b - t_a, 0.0f);
            const float cd = cb + (c - cb) * __expf(-dl * dt);
            s_h[row][k] = og * tanh_f(cd);
        }
    }
    __syncthreads();
    const int t = t0 + ty;
    if (t >= SEQ - 1) return;
    float acc = s_b[tx];
#pragma unroll
    for (int k = 0; k < HID; ++k) acc = fmaf(s_h[ty][k], s_w[k * NF + tx], acc);
    out_int[((size_t)b * (SEQ - 1) + t) * NF + tx] = softplus_f(acc);
}

extern "C" void kernel_launch(void* const* d_in, const int* in_sizes, int n_in,
                              void* d_out, int out_size, void* d_ws, size_t ws_size,
                              hipStream_t stream) {
    const void* batch = d_in[0];
    const void* W_rec = d_in[1];
    const void* b_rec = d_in[2];
    const void* W_int = d_in[3];
    const void* b_int = d_in[4];
    float* out = (float*)d_out;

    // ws layout: [0,256) flag | [256, 256+hb) fp32 h | [256+hb, ...) xz fp32
    const size_t hb  = (size_t)BATCHN * SEQ * HID * sizeof(float);   // 33.5 MB
    const size_t xzb = (size_t)BATCHN * SEQ * G7  * sizeof(float);   // 235 MB
    int*   flag = (ws_size >= 4) ? (int*)d_ws : nullptr;
    float* h_ws = (float*)((char*)d_ws + 256);
    float* xz   = (float*)((char*)d_ws + 256 + hb);
    const int have_h  = (ws_size >= 256 + hb) ? 1 : 0;          // launch-constant
    const int have_xz = (ws_size >= 256 + hb + xzb) ? 1 : 0;    // launch-constant

    if (flag) detect_dtype<<<1, 64, 0, stream>>>(batch, flag);

    float* out_int = out + 4 * (size_t)BATCHN * SEQ * HID;

    if (have_xz) {
        xproj_gemm<<<(BATCHN * SEQ) / 64, G7, 0, stream>>>(batch, W_rec, b_rec, xz, flag);
        ctlstm_rec_xzw<<<BATCHN, REC_T, 0, stream>>>(batch, W_rec, xz, out, h_ws, flag);
        intensity_ws<<<dim3((SEQ - 1 + 7) / 8, BATCHN), dim3(32, 8), 0, stream>>>(
            h_ws, W_int, b_int, out_int, flag);
    } else if (have_h) {
        ctlstm_rec<<<BATCHN, G7, 0, stream>>>(batch, W_rec, b_rec, out, h_ws, 1, flag);
        intensity_ws<<<dim3((SEQ - 1 + 7) / 8, BATCHN), dim3(32, 8), 0, stream>>>(
            h_ws, W_int, b_int, out_int, flag);
    } else {
        ctlstm_rec<<<BATCHN, G7, 0, stream>>>(batch, W_rec, b_rec, out, h_ws, 0, flag);
        intensity_rec<<<dim3((SEQ - 1 + 7) / 8, BATCHN), dim3(32, 8), 0, stream>>>(
            batch, out, W_int, b_int, out_int, flag);
    }
}